// Round 5
// baseline (349.561 us; speedup 1.0000x reference)
//
#include <hip/hip_runtime.h>

#define D 128
#define SCAN_B 1024
#define WPADH 132   // LDS row stride in halfs (264 B): conflict-free b64 reads

static inline int ceil_div_ll(long long a, int b) { return (int)((a + b - 1) / b); }

typedef unsigned int uint32;
typedef unsigned short ushort16;

__device__ __forceinline__ float blo(uint32 u) { return __uint_as_float(u << 16); }
__device__ __forceinline__ float bhi(uint32 u) { return __uint_as_float(u & 0xffff0000u); }
// pack two f32 -> bf16x2 (RTNE)
__device__ __forceinline__ uint32 bpack(float a, float b) {
    uint32 ua = __float_as_uint(a);
    uint32 ub = __float_as_uint(b);
    ua += 0x7fffu + ((ua >> 16) & 1u);
    ub += 0x7fffu + ((ub >> 16) & 1u);
    return (ua >> 16) | (ub & 0xffff0000u);
}
__device__ __forceinline__ ushort16 b1(float a) {
    uint32 ua = __float_as_uint(a);
    ua += 0x7fffu + ((ua >> 16) & 1u);
    return (ushort16)(ua >> 16);
}

// deg[i] = 1.0 (self loop), cnt[i] = 0
__global__ void k_init(float* __restrict__ deg, int* __restrict__ cnt, int n) {
    int i = blockIdx.x * blockDim.x + threadIdx.x;
    if (i < n) { deg[i] = 1.0f; cnt[i] = 0; }
}

__global__ void k_count(const int* __restrict__ ei, float* __restrict__ deg,
                        int* __restrict__ cnt, int E) {
    int e = blockIdx.x * blockDim.x + threadIdx.x;
    if (e < E) {
        int r = ei[e];
        int c = ei[(long long)E + e];
        unsafeAtomicAdd(&deg[c], 1.0f);
        atomicAdd(&cnt[r], 1);
    }
}

__global__ void k_deg_finalize(float* __restrict__ deg, int n) {
    int i = blockIdx.x * blockDim.x + threadIdx.x;
    if (i < n) deg[i] = 1.0f / sqrtf(deg[i]);
}

// ---- two-level exclusive scan of cnt -> rp ----
__global__ __launch_bounds__(SCAN_B) void k_scan1(const int* __restrict__ cnt,
                                                  int* __restrict__ rp,
                                                  int* __restrict__ bsum, int n) {
    __shared__ int sh[SCAN_B];
    const int tid = threadIdx.x;
    const int i = blockIdx.x * SCAN_B + tid;
    int v = (i < n) ? cnt[i] : 0;
    sh[tid] = v;
    __syncthreads();
    for (int off = 1; off < SCAN_B; off <<= 1) {
        int t = (tid >= off) ? sh[tid - off] : 0;
        __syncthreads();
        sh[tid] += t;
        __syncthreads();
    }
    if (i < n) rp[i] = sh[tid] - v;
    if (tid == SCAN_B - 1) bsum[blockIdx.x] = sh[SCAN_B - 1];
}

__global__ __launch_bounds__(SCAN_B) void k_scan2(int* __restrict__ bsum,
                                                  int* __restrict__ rp, int nb, int n) {
    __shared__ int sh[SCAN_B];
    const int tid = threadIdx.x;
    int v = (tid < nb) ? bsum[tid] : 0;
    sh[tid] = v;
    __syncthreads();
    for (int off = 1; off < SCAN_B; off <<= 1) {
        int t = (tid >= off) ? sh[tid - off] : 0;
        __syncthreads();
        sh[tid] += t;
        __syncthreads();
    }
    if (tid < nb) bsum[tid] = sh[tid] - v;
    if (tid == SCAN_B - 1) rp[n] = sh[SCAN_B - 1];
}

__global__ void k_scan3(int* __restrict__ rp, int* __restrict__ cur,
                        const int* __restrict__ bsum, int n) {
    int i = blockIdx.x * blockDim.x + threadIdx.x;
    if (i < n) {
        int v = rp[i] + bsum[i >> 10];
        rp[i] = v;
        cur[i] = v;
    }
}

// scatter edges into CSR slots as packed {col, weight_bits}
__global__ void k_fill(const int* __restrict__ ei, const float* __restrict__ dinv,
                       int* __restrict__ cur, int2* __restrict__ e8, int E) {
    int e = blockIdx.x * blockDim.x + threadIdx.x;
    if (e < E) {
        int r = ei[e];
        int c = ei[(long long)E + e];
        float w = dinv[r] * dinv[c];
        int pos = atomicAdd(&cur[r], 1);
        int2 p; p.x = c; p.y = __float_as_int(w);
        e8[pos] = p;
    }
}

// x (f32) -> xh (bf16 RTNE), 2 floats -> 1 uint per thread
__global__ void k_cvt(const float2* __restrict__ x, uint32* __restrict__ xh, long long total) {
    long long i = (long long)blockIdx.x * blockDim.x + threadIdx.x;
    if (i < total) {
        float2 v = x[i];
        xh[i] = bpack(v.x, v.y);
    }
}

// out[r][:] = dinv[r]^2 * xh[r][:] + sum_e w_e * xh[col_e][:]
// one wave per row; lane holds bf16x2 (uint). OUT_BF16: write bf16x2, else float2.
template <bool OUT_BF16>
__global__ __launch_bounds__(256) void k_spmm(const uint32* __restrict__ xh,
                                              const int* __restrict__ rp,
                                              const int2* __restrict__ e8,
                                              const float* __restrict__ dinv,
                                              void* __restrict__ outp, int n) {
    const int row = blockIdx.x * 4 + (threadIdx.x >> 6);
    if (row >= n) return;
    const int lane = threadIdx.x & 63;

    float s = dinv[row];
    s *= s;
    const uint32 sv = xh[(long long)row * 64 + lane];
    float ax = s * blo(sv);
    float ay = s * bhi(sv);

    int e = rp[row];
    const int end = rp[row + 1];
    for (; e + 3 < end; e += 4) {
        const int2 p0 = e8[e], p1 = e8[e + 1], p2 = e8[e + 2], p3 = e8[e + 3];
        const uint32 v0 = xh[(long long)p0.x * 64 + lane];
        const uint32 v1 = xh[(long long)p1.x * 64 + lane];
        const uint32 v2 = xh[(long long)p2.x * 64 + lane];
        const uint32 v3 = xh[(long long)p3.x * 64 + lane];
        const float w0 = __int_as_float(p0.y), w1 = __int_as_float(p1.y);
        const float w2 = __int_as_float(p2.y), w3 = __int_as_float(p3.y);
        ax += w0 * blo(v0) + w1 * blo(v1) + w2 * blo(v2) + w3 * blo(v3);
        ay += w0 * bhi(v0) + w1 * bhi(v1) + w2 * bhi(v2) + w3 * bhi(v3);
    }
    for (; e < end; ++e) {
        const int2 p = e8[e];
        const uint32 v = xh[(long long)p.x * 64 + lane];
        const float w = __int_as_float(p.y);
        ax += w * blo(v);
        ay += w * bhi(v);
    }
    if (OUT_BF16) {
        ((uint32*)outp)[(long long)row * 64 + lane] = bpack(ax, ay);
    } else {
        float2 o; o.x = ax; o.y = ay;
        ((float2*)outp)[(long long)row * 64 + lane] = o;
    }
}

// xout[r][:] = xin[r][:] @ W^T + b, 128 rows x all 128 cols per block.
// W staged bf16 in LDS (34 KB, conflict-free). x rows read from global with
// 16-lane broadcast. In-place safe: __syncthreads() between reads and stores;
// clamped threads duplicate-write identical values.
__global__ __launch_bounds__(256, 4) void k_gemm(const float* xin,
                                                 const float* __restrict__ Wm,
                                                 const float* __restrict__ bias,
                                                 float* xout, int n) {
    __shared__ ushort16 shw[128 * WPADH];   // ~33.8 KB
    __shared__ float shb[128];

    const int tid = threadIdx.x;
    const long long rowbase = (long long)blockIdx.x * 128;

    // stage W as bf16: shw[j][k], j = output col
    for (int idx = tid; idx < 128 * 32; idx += 256) {
        const int j = idx >> 5;
        const int k4 = idx & 31;
        const float4 v = *(const float4*)(Wm + ((long long)j << 7) + (k4 << 2));
        ushort16* d = shw + j * WPADH + (k4 << 2);
        d[0] = b1(v.x); d[1] = b1(v.y); d[2] = b1(v.z); d[3] = b1(v.w);
    }
    if (tid < 128) shb[tid] = bias[tid];
    __syncthreads();

    const int ty = tid >> 4;   // 0..15 -> 8 rows each
    const int tx = tid & 15;   // cols tx + 16*m, m=0..7

    long long rs = rowbase + (long long)ty * 8;
    if (rs + 8 > n) rs = (long long)n - 8;   // window clamp (duplicates benign)
    const float* xbase = xin + (rs << 7);

    float acc[8][8];
#pragma unroll
    for (int i = 0; i < 8; ++i)
#pragma unroll
        for (int m = 0; m < 8; ++m) acc[i][m] = 0.0f;

    for (int k4 = 0; k4 < 32; ++k4) {
        const int ko = k4 << 2;
        float4 xr[8];
#pragma unroll
        for (int i = 0; i < 8; ++i) xr[i] = *(const float4*)(xbase + (i << 7) + ko);
#pragma unroll
        for (int m = 0; m < 8; ++m) {
            const uint2 w2 = *(const uint2*)(shw + (tx + (m << 4)) * WPADH + ko);
            const float f0 = blo(w2.x), f1 = bhi(w2.x), f2 = blo(w2.y), f3 = bhi(w2.y);
#pragma unroll
            for (int i = 0; i < 8; ++i)
                acc[i][m] += xr[i].x * f0 + xr[i].y * f1 + xr[i].z * f2 + xr[i].w * f3;
        }
    }

    __syncthreads();   // all reads done before any in-place store

#pragma unroll
    for (int i = 0; i < 8; ++i) {
        float* orow = xout + ((rs + i) << 7);
#pragma unroll
        for (int m = 0; m < 8; ++m) {
            const int c = tx + (m << 4);
            orow[c] = acc[i][m] + shb[c];
        }
    }
}

extern "C" void kernel_launch(void* const* d_in, const int* in_sizes, int n_in,
                              void* d_out, int out_size, void* d_ws, size_t ws_size,
                              hipStream_t stream) {
    const float* x = (const float*)d_in[0];
    const int* ei = (const int*)d_in[1];
    const float* Wm = (const float*)d_in[2];
    const float* bias = (const float*)d_in[3];
    float* out = (float*)d_out;

    const int n = in_sizes[0] / D;
    const int E = in_sizes[1] / 2;
    const int NB = (n + SCAN_B - 1) / SCAN_B;

    char* ws = (char*)d_ws;
    size_t off = 0;
    auto alloc = [&](long long bytes) {
        void* p = ws + off;
        off += (size_t)((bytes + 511) & ~511LL);
        return p;
    };
    float* dinv  = (float*)alloc((long long)n * 4);
    int* cnt     = (int*)alloc((long long)n * 4);
    int* rp      = (int*)alloc((long long)(n + 1) * 4);
    int* cur     = (int*)alloc((long long)n * 4);
    int* bsum    = (int*)alloc((long long)SCAN_B * 4);
    int2* e8     = (int2*)alloc((long long)E * 8);
    uint32* xh   = (uint32*)alloc((long long)n * 64 * 4);   // bf16 x
    uint32* x1h  = (uint32*)alloc((long long)n * 64 * 4);   // bf16 hop-1 out

    const int B = 256;

    k_init<<<ceil_div_ll(n, B), B, 0, stream>>>(dinv, cnt, n);
    k_count<<<ceil_div_ll(E, B), B, 0, stream>>>(ei, dinv, cnt, E);
    k_deg_finalize<<<ceil_div_ll(n, B), B, 0, stream>>>(dinv, n);

    k_scan1<<<NB, SCAN_B, 0, stream>>>(cnt, rp, bsum, n);
    k_scan2<<<1, SCAN_B, 0, stream>>>(bsum, rp, NB, n);
    k_scan3<<<ceil_div_ll(n, B), B, 0, stream>>>(rp, cur, bsum, n);
    k_fill<<<ceil_div_ll(E, B), B, 0, stream>>>(ei, dinv, cur, e8, E);

    // x -> bf16
    const long long tot2 = (long long)n * 64;
    k_cvt<<<ceil_div_ll(tot2, B), B, 0, stream>>>((const float2*)x, xh, tot2);

    // hop 1 (bf16 out), hop 2 (f32 out, into d_out)
    k_spmm<true><<<ceil_div_ll(n, 4), B, 0, stream>>>(xh, rp, e8, dinv, (void*)x1h, n);
    k_spmm<false><<<ceil_div_ll(n, 4), B, 0, stream>>>(x1h, rp, e8, dinv, (void*)out, n);

    // out = out @ W^T + b (in place, barrier-protected)
    k_gemm<<<ceil_div_ll(n, 128), B, 0, stream>>>(out, Wm, bias, out, n);
}